// Round 1
// baseline (359.137 us; speedup 1.0000x reference)
//
#include <hip/hip_runtime.h>
#include <math.h>

#define HDIM 100
#define NFACT 262144
#define NBLK 2048          // NFACT / 128

// ws layout (float offsets)
#define WS_W1T    0                       // 200*100 transposed W1 (W1T[k][j])
#define WS_LOGITS (200*HDIM)              // NFACT logits
#define WS_BMAX   (WS_LOGITS + NFACT)     // NBLK per-block maxes
#define WS_GMAX   (WS_BMAX + NBLK)        // 1
#define WS_S      (WS_GMAX + 1)           // 1 softmax denom
#define WS_CACC   (WS_S + 1)              // HDIM weighted-sum accumulator
// total ~284294 floats ~= 1.09 MB of ws

__global__ __launch_bounds__(256) void k_transpose_w1(
        const float* __restrict__ W1, float* __restrict__ w1t) {
    int i = blockIdx.x * 256 + threadIdx.x;   // over 2*H*H = 20000
    if (i < 2 * HDIM * HDIM) {
        int j = i / (2 * HDIM);
        int k = i % (2 * HDIM);
        w1t[k * HDIM + j] = W1[i];
    }
}

__device__ __forceinline__ float tanh_fast(float x) {
    // tanh(x) = 1 - 2/(1+exp(2x)); saturates correctly for |x| large
    float e = __expf(2.0f * x);
    return 1.0f - 2.0f / (1.0f + e);
}

// One thread computes 50 hidden neurons [JBASE, JBASE+50) for fact `ft`,
// returns partial g = sum tanh(h_j)*W2[j].
template<int JBASE>
__device__ __forceinline__ float compute_half(
        const float* __restrict__ ftile, int ft,
        const float* __restrict__ w1t,
        const float* __restrict__ b1,
        const float* __restrict__ W2,
        const float* __restrict__ oc,
        const float* __restrict__ mvec) {
    float h[50];
    #pragma unroll
    for (int jj = 0; jj < 50; jj++) h[jj] = b1[JBASE + jj];

    #pragma unroll 2
    for (int k = 0; k < HDIM; k++) {
        float fk = ftile[k * 129 + ft];          // LDS, lanes consecutive -> conflict-free
        float za = fabsf(fk - oc[k]);            // oc/m uniform -> scalar loads
        float zb = fabsf(fk - mvec[k]);
        const float* wa = &w1t[k * HDIM + JBASE];          // uniform contiguous rows
        const float* wb = &w1t[(k + HDIM) * HDIM + JBASE]; // -> s_load path
        #pragma unroll
        for (int jj = 0; jj < 50; jj++) {
            h[jj] = fmaf(za, wa[jj], h[jj]);
            h[jj] = fmaf(zb, wb[jj], h[jj]);
        }
    }
    float g = 0.f;
    #pragma unroll
    for (int jj = 0; jj < 50; jj++)
        g = fmaf(tanh_fast(h[jj]), W2[JBASE + jj], g);
    return g;
}

// 256 threads / 128 facts per block. Two thread-halves split the 100 neurons.
__global__ __launch_bounds__(256) void k_logits(
        const float* __restrict__ fe,
        const float* __restrict__ oc,
        const float* __restrict__ mvec,
        const float* __restrict__ b1,
        const float* __restrict__ W2,
        const float* __restrict__ b2,
        float* __restrict__ ws) {
    __shared__ float ftile[HDIM * 129];   // [k][fact], padded stride 129
    __shared__ float pa[256];
    __shared__ float wred[4];

    int t = threadIdx.x;
    long n0 = (long)blockIdx.x * 128;

    // Stage 128 fact rows transposed into LDS; coalesced float2 global reads.
    const float2* f2 = (const float2*)(fe + n0 * HDIM);
    #pragma unroll
    for (int i = 0; i < 25; i++) {
        int e2 = t + i * 256;            // 0..6399, fact = e2/50, pair = e2%50
        float2 v = f2[e2];
        int fact = e2 / 50;
        int kp = (e2 % 50) * 2;
        ftile[kp * 129 + fact] = v.x;
        ftile[(kp + 1) * 129 + fact] = v.y;
    }
    __syncthreads();

    float pg;
    if (t < 128) pg = compute_half<0>(ftile, t, ws + WS_W1T, b1, W2, oc, mvec);
    else         pg = compute_half<50>(ftile, t - 128, ws + WS_W1T, b1, W2, oc, mvec);
    pa[t] = pg;
    __syncthreads();

    float mv = -1e30f;
    if (t < 128) {
        float logit = pa[t] + pa[t + 128] + b2[0];
        ws[WS_LOGITS + n0 + t] = logit;
        mv = logit;
    }
    #pragma unroll
    for (int off = 32; off; off >>= 1) mv = fmaxf(mv, __shfl_down(mv, off));
    if ((t & 63) == 0) wred[t >> 6] = mv;
    __syncthreads();
    if (t == 0) ws[WS_BMAX + blockIdx.x] = fmaxf(wred[0], wred[1]);
}

__global__ __launch_bounds__(256) void k_reduce_max_zero(float* __restrict__ ws) {
    __shared__ float red[4];
    int t = threadIdx.x;
    float mv = -1e30f;
    for (int i = t; i < NBLK; i += 256) mv = fmaxf(mv, ws[WS_BMAX + i]);
    #pragma unroll
    for (int off = 32; off; off >>= 1) mv = fmaxf(mv, __shfl_down(mv, off));
    if ((t & 63) == 0) red[t >> 6] = mv;
    __syncthreads();
    if (t == 0) {
        ws[WS_GMAX] = fmaxf(fmaxf(red[0], red[1]), fmaxf(red[2], red[3]));
        ws[WS_S] = 0.f;
    }
    if (t < HDIM) ws[WS_CACC + t] = 0.f;
}

__global__ __launch_bounds__(128) void k_wsum(
        const float* __restrict__ fe, float* __restrict__ ws) {
    __shared__ float wls[128];
    __shared__ float sred[2];
    int t = threadIdx.x;
    long n0 = (long)blockIdx.x * 128;
    float gmax = ws[WS_GMAX];
    float lw = __expf(ws[WS_LOGITS + n0 + t] - gmax);
    wls[t] = lw;
    float s = lw;
    #pragma unroll
    for (int off = 32; off; off >>= 1) s += __shfl_down(s, off);
    if ((t & 63) == 0) sred[t >> 6] = s;
    __syncthreads();
    if (t == 0) atomicAdd(&ws[WS_S], sred[0] + sred[1]);

    if (t < HDIM) {
        float cl = 0.f;
        const float* fp = fe + n0 * HDIM + t;
        #pragma unroll 4
        for (int n = 0; n < 128; n++) cl = fmaf(wls[n], fp[n * HDIM], cl);
        atomicAdd(&ws[WS_CACC + t], cl);
    }
}

__global__ __launch_bounds__(128) void k_final(
        const float* __restrict__ mvec,
        const float* __restrict__ oc,
        const float* __restrict__ W3,
        const float* __restrict__ b3,
        const float* __restrict__ ws,
        float* __restrict__ out) {
    __shared__ float v[3 * HDIM];
    int t = threadIdx.x;
    float Sinv = 1.0f / ws[WS_S];
    if (t < HDIM) {
        v[t] = mvec[t];
        v[HDIM + t] = ws[WS_CACC + t] * Sinv;
        v[2 * HDIM + t] = oc[t];
    }
    __syncthreads();
    if (t < HDIM) {
        float acc = b3[t];
        const float* wr = W3 + t * 3 * HDIM;
        #pragma unroll 4
        for (int k = 0; k < 3 * HDIM; k++) acc = fmaf(wr[k], v[k], acc);
        out[t] = fmaxf(acc, 0.f);
    }
}

extern "C" void kernel_launch(void* const* d_in, const int* in_sizes, int n_in,
                              void* d_out, int out_size, void* d_ws, size_t ws_size,
                              hipStream_t stream) {
    const float* mvec = (const float*)d_in[0];
    const float* oh   = (const float*)d_in[1];   // [1,1,H] -> flat H
    const float* fe   = (const float*)d_in[2];
    const float* W1   = (const float*)d_in[3];
    const float* b1   = (const float*)d_in[4];
    const float* W2   = (const float*)d_in[5];
    const float* b2   = (const float*)d_in[6];
    const float* W3   = (const float*)d_in[7];
    const float* b3   = (const float*)d_in[8];
    float* ws  = (float*)d_ws;
    float* out = (float*)d_out;

    k_transpose_w1<<<(2 * HDIM * HDIM + 255) / 256, 256, 0, stream>>>(W1, ws + WS_W1T);
    k_logits<<<NBLK, 256, 0, stream>>>(fe, oh, mvec, b1, W2, b2, ws);
    k_reduce_max_zero<<<1, 256, 0, stream>>>(ws);
    k_wsum<<<NBLK, 128, 0, stream>>>(fe, ws);
    k_final<<<1, 128, 0, stream>>>(mvec, oh, W3, b3, ws, out);
}

// Round 2
// 137.713 us; speedup vs baseline: 2.6079x; 2.6079x over previous
//
#include <hip/hip_runtime.h>
#include <math.h>

#define HDIM 100
#define NFACT 262144

using short8 = __attribute__((ext_vector_type(8))) short;
using f32x4  = __attribute__((ext_vector_type(4))) float;

// ---------------- ws float-offset layout ----------------
#define WS_B      0                       // 14336 floats = 7*8*64 uint4 B-fragments (bf16 bits)
#define WS_LOGITS 14336                   // NFACT
#define WS_BMAX   (WS_LOGITS + NFACT)     // 2048 per-block maxes
#define WS_GMAX   (WS_BMAX + 2048)        // 1
#define WS_SP     (WS_GMAX + 1)           // 1024 partial softmax denoms
#define WS_PC     (WS_SP + 1024)          // 1024*100 partial weighted sums [block][h]
// end = 381953 floats (~1.53 MB)

__device__ __forceinline__ unsigned short f2bf(float x) {
    unsigned u = __builtin_bit_cast(unsigned, x);
    u += 0x7FFFu + ((u >> 16) & 1u);          // RNE round to bf16
    return (unsigned short)(u >> 16);
}

__device__ __forceinline__ float tanh_fast(float x) {
    float e = __expf(2.0f * x);
    return 1.0f - 2.0f / (1.0f + e);
}

// ---- Precompute W1 as MFMA B-fragments (bf16), frag order [jt][kc][lane][8] ----
// B[k][j]: j = jt*16 + (lane&15); k = kc*32 + (lane>>4)*8 + e.
// k in [0,128): z-half A (f - oc), real if (k&127) < 100; k in [128,256): half B (f - m).
__global__ __launch_bounds__(256) void k_prep_b(const float* __restrict__ W1,
                                                float* __restrict__ ws) {
    int t = blockIdx.x * 256 + threadIdx.x;   // 0..3583
    if (t >= 7 * 8 * 64) return;
    int lane = t & 63;
    int kc = (t >> 6) & 7;
    int jt = t >> 9;
    int g = lane >> 4, r = lane & 15;
    int j = jt * 16 + r;
    unsigned short v[8];
    #pragma unroll
    for (int e = 0; e < 8; e++) {
        int kglob = kc * 32 + g * 8 + e;
        int half = kglob >> 7;
        int koff = kglob & 127;
        float x = 0.f;
        if (j < HDIM && koff < HDIM) x = W1[j * 200 + half * HDIM + koff];
        v[e] = f2bf(x);
    }
    uint4 d;
    d.x = (unsigned)v[0] | ((unsigned)v[1] << 16);
    d.y = (unsigned)v[2] | ((unsigned)v[3] << 16);
    d.z = (unsigned)v[4] | ((unsigned)v[5] << 16);
    d.w = (unsigned)v[6] | ((unsigned)v[7] << 16);
    ((uint4*)(ws + WS_B))[t] = d;
}

// ---------------- logits via MFMA ----------------
#define FT_STRIDE 132                 // 132 % 32 == 4 -> balanced banks; >= 128 so koff<=127 fits
#define OF_FT  0                      // 128*132 = 16896 floats
#define OF_B   16896                  // 14336 floats (3584 uint4)
#define OF_OCM 31232                  // 256 (oc padded 128 | m padded 128)
#define OF_W2  31488                  // 112
#define OF_B1  31600                  // 112
#define OF_GV  31712                  // 128
#define OF_RED 31840                  // 8
#define SMEM_FLOATS 31848             // 127392 B LDS

__global__ __launch_bounds__(256) void k_logits(
        const float* __restrict__ fe,
        const float* __restrict__ oc,
        const float* __restrict__ mvec,
        const float* __restrict__ b1,
        const float* __restrict__ W2,
        float* __restrict__ ws) {
    __shared__ float smem[SMEM_FLOATS];
    int t = threadIdx.x;
    long n0 = (long)blockIdx.x * 128;

    // stage B fragments (57344 B) from ws
    {
        const uint4* src = (const uint4*)(ws + WS_B);
        uint4* dst = (uint4*)(smem + OF_B);
        #pragma unroll
        for (int i = 0; i < 14; i++) dst[t + i * 256] = src[t + i * 256];
    }
    // stage 128 fact rows (100 floats each) coalesced, then zero pad cols 100..131
    {
        const float4* src = (const float4*)(fe + n0 * HDIM);
        #pragma unroll
        for (int i = 0; i < 13; i++) {
            int e4 = t + i * 256;
            if (e4 < 3200) {
                float4 v = src[e4];
                int f = e4 / 25, off = (e4 % 25) * 4;
                *(float4*)(smem + OF_FT + f * FT_STRIDE + off) = v;
            }
        }
        for (int i = t; i < 1024; i += 256) {
            int f = i >> 3, q = i & 7;
            *(float4*)(smem + OF_FT + f * FT_STRIDE + 100 + q * 4) = make_float4(0, 0, 0, 0);
        }
    }
    if (t < 128)      smem[OF_OCM + t] = (t < HDIM) ? oc[t] : 0.f;
    else              { int i = t - 128; smem[OF_OCM + 128 + i] = (i < HDIM) ? mvec[i] : 0.f; }
    if (t < 112) smem[OF_W2 + t] = (t < HDIM) ? W2[t] : 0.f;
    if (t < 112) smem[OF_B1 + t] = (t < HDIM) ? b1[t] : 0.f;
    __syncthreads();

    int w = t >> 6, lane = t & 63;
    int g = lane >> 4, r = lane & 15;

    // Build A fragments: z = |f - oc| (k<128 half) / |f - m| (k>=128 half), bf16.
    short8 afrag[2][8];
    #pragma unroll
    for (int tile = 0; tile < 2; tile++) {
        int fl = w * 32 + tile * 16 + r;
        const float* frow = smem + OF_FT + fl * FT_STRIDE;
        #pragma unroll
        for (int kc = 0; kc < 8; kc++) {
            int half = kc >> 2;
            int koff = (kc & 3) * 32 + g * 8;
            float4 fa = *(const float4*)(frow + koff);
            float4 fb = *(const float4*)(frow + koff + 4);
            const float* ocp = smem + OF_OCM + half * 128 + koff;
            float z[8];
            z[0] = fabsf(fa.x - ocp[0]); z[1] = fabsf(fa.y - ocp[1]);
            z[2] = fabsf(fa.z - ocp[2]); z[3] = fabsf(fa.w - ocp[3]);
            z[4] = fabsf(fb.x - ocp[4]); z[5] = fabsf(fb.y - ocp[5]);
            z[6] = fabsf(fb.z - ocp[6]); z[7] = fabsf(fb.w - ocp[7]);
            union { unsigned short us[8]; short8 v; } u;
            #pragma unroll
            for (int e = 0; e < 8; e++) u.us[e] = f2bf(z[e]);
            afrag[tile][kc] = u.v;
        }
    }

    // GEMM + fused epilogue: h = acc + b1[j]; g += tanh(h) * W2[j]
    float gpart[2][4] = {{0, 0, 0, 0}, {0, 0, 0, 0}};
    const uint4* Bl = (const uint4*)(smem + OF_B);
    #pragma unroll
    for (int jt = 0; jt < 7; jt++) {
        f32x4 acc0 = {0, 0, 0, 0}, acc1 = {0, 0, 0, 0};
        #pragma unroll
        for (int kc = 0; kc < 8; kc++) {
            union { uint4 u; short8 v; } b;
            b.u = Bl[(jt * 8 + kc) * 64 + lane];
            acc0 = __builtin_amdgcn_mfma_f32_16x16x32_bf16(afrag[0][kc], b.v, acc0, 0, 0, 0);
            acc1 = __builtin_amdgcn_mfma_f32_16x16x32_bf16(afrag[1][kc], b.v, acc1, 0, 0, 0);
        }
        float w2j = smem[OF_W2 + jt * 16 + r];
        float b1j = smem[OF_B1 + jt * 16 + r];
        #pragma unroll
        for (int q = 0; q < 4; q++) {
            gpart[0][q] = fmaf(tanh_fast(acc0[q] + b1j), w2j, gpart[0][q]);
            gpart[1][q] = fmaf(tanh_fast(acc1[q] + b1j), w2j, gpart[1][q]);
        }
    }

    // reduce over j (lane&15) within each 16-lane group; C row = fact = g*4+q
    #pragma unroll
    for (int tile = 0; tile < 2; tile++) {
        #pragma unroll
        for (int q = 0; q < 4; q++) {
            float v = gpart[tile][q];
            v += __shfl_xor(v, 1); v += __shfl_xor(v, 2);
            v += __shfl_xor(v, 4); v += __shfl_xor(v, 8);
            if (r == 0) smem[OF_GV + w * 32 + tile * 16 + g * 4 + q] = v;
        }
    }
    __syncthreads();

    float logit = -1e30f;
    if (t < 128) {
        logit = smem[OF_GV + t];              // b2 dropped: softmax-invariant
        ws[WS_LOGITS + n0 + t] = logit;
    }
    float mv = logit;
    #pragma unroll
    for (int off = 32; off; off >>= 1) mv = fmaxf(mv, __shfl_down(mv, off));
    if ((t & 63) == 0) smem[OF_RED + (t >> 6)] = mv;
    __syncthreads();
    if (t == 0)
        ws[WS_BMAX + blockIdx.x] = fmaxf(fmaxf(smem[OF_RED], smem[OF_RED + 1]),
                                         fmaxf(smem[OF_RED + 2], smem[OF_RED + 3]));
}

__global__ __launch_bounds__(256) void k_gmax(float* __restrict__ ws) {
    __shared__ float red[4];
    int t = threadIdx.x;
    float mv = -1e30f;
    for (int i = t; i < 2048; i += 256) mv = fmaxf(mv, ws[WS_BMAX + i]);
    #pragma unroll
    for (int off = 32; off; off >>= 1) mv = fmaxf(mv, __shfl_down(mv, off));
    if ((t & 63) == 0) red[t >> 6] = mv;
    __syncthreads();
    if (t == 0) ws[WS_GMAX] = fmaxf(fmaxf(red[0], red[1]), fmaxf(red[2], red[3]));
}

// 256 facts/block; per-block partial S and partial c[100] (no atomics)
__global__ __launch_bounds__(256) void k_wsum(const float* __restrict__ fe,
                                              float* __restrict__ ws) {
    __shared__ float wls[256];
    __shared__ float sred[4];
    __shared__ float c2r[5][50][2];
    int t = threadIdx.x;
    long n0 = (long)blockIdx.x * 256;
    float gmax = ws[WS_GMAX];
    float lw = __expf(ws[WS_LOGITS + n0 + t] - gmax);
    wls[t] = lw;
    float s = lw;
    #pragma unroll
    for (int off = 32; off; off >>= 1) s += __shfl_down(s, off);
    if ((t & 63) == 0) sred[t >> 6] = s;
    __syncthreads();
    if (t == 0) ws[WS_SP + blockIdx.x] = (sred[0] + sred[1]) + (sred[2] + sred[3]);

    if (t < 250) {
        int sl = t / 50, p = t % 50;
        const float2* f2 = (const float2*)(fe + n0 * HDIM);
        float cx = 0.f, cy = 0.f;
        #pragma unroll 4
        for (int n = sl; n < 256; n += 5) {
            float wn = wls[n];
            float2 v = f2[n * 50 + p];
            cx = fmaf(wn, v.x, cx);
            cy = fmaf(wn, v.y, cy);
        }
        c2r[sl][p][0] = cx; c2r[sl][p][1] = cy;
    }
    __syncthreads();
    if (t < 50) {
        float cx = 0.f, cy = 0.f;
        #pragma unroll
        for (int sl = 0; sl < 5; sl++) { cx += c2r[sl][t][0]; cy += c2r[sl][t][1]; }
        ws[WS_PC + (long)blockIdx.x * HDIM + 2 * t]     = cx;
        ws[WS_PC + (long)blockIdx.x * HDIM + 2 * t + 1] = cy;
    }
}

// Sum partials, normalize, gated update
__global__ __launch_bounds__(1024) void k_final(
        const float* __restrict__ mvec,
        const float* __restrict__ oc,
        const float* __restrict__ W3,
        const float* __restrict__ b3,
        const float* __restrict__ ws,
        float* __restrict__ out) {
    __shared__ float sr[256];
    __shared__ float csl[1000];
    __shared__ float vv[300];
    __shared__ float Sval;
    int t = threadIdx.x;
    if (t < 256) {
        float a = 0.f;
        #pragma unroll
        for (int k = 0; k < 4; k++) a += ws[WS_SP + t + k * 256];
        sr[t] = a;
    }
    __syncthreads();
    if (t < 128) sr[t] += sr[t + 128];
    __syncthreads();
    if (t < 64) sr[t] += sr[t + 64];
    __syncthreads();
    if (t == 0) {
        float a = 0.f;
        #pragma unroll
        for (int k = 0; k < 64; k++) a += sr[k];
        Sval = a;
    }
    if (t < 1000) {
        int sl = t / 100, h = t % 100;
        float a = 0.f;
        #pragma unroll 4
        for (int b = sl; b < 1024; b += 10) a += ws[WS_PC + b * HDIM + h];
        csl[t] = a;
    }
    __syncthreads();
    if (t < 100) {
        float c = 0.f;
        #pragma unroll
        for (int sl = 0; sl < 10; sl++) c += csl[sl * 100 + t];
        vv[t] = mvec[t];
        vv[100 + t] = c / Sval;
        vv[200 + t] = oc[t];
    }
    __syncthreads();
    if (t < 100) {
        float a = b3[t];
        const float* wr = W3 + t * 300;
        #pragma unroll 4
        for (int k = 0; k < 300; k++) a = fmaf(wr[k], vv[k], a);
        out[t] = fmaxf(a, 0.f);
    }
}

extern "C" void kernel_launch(void* const* d_in, const int* in_sizes, int n_in,
                              void* d_out, int out_size, void* d_ws, size_t ws_size,
                              hipStream_t stream) {
    const float* mvec = (const float*)d_in[0];
    const float* oh   = (const float*)d_in[1];
    const float* fe   = (const float*)d_in[2];
    const float* W1   = (const float*)d_in[3];
    const float* b1   = (const float*)d_in[4];
    const float* W2   = (const float*)d_in[5];
    const float* W3   = (const float*)d_in[7];
    const float* b3   = (const float*)d_in[8];
    float* ws  = (float*)d_ws;
    float* out = (float*)d_out;

    k_prep_b<<<14, 256, 0, stream>>>(W1, ws);
    k_logits<<<NFACT / 128, 256, 0, stream>>>(fe, oh, mvec, b1, W2, ws);
    k_gmax<<<1, 256, 0, stream>>>(ws);
    k_wsum<<<NFACT / 256, 256, 0, stream>>>(fe, ws);
    k_final<<<1, 1024, 0, stream>>>(mvec, oh, W3, b3, ws, out);
}

// Round 3
// 105.167 us; speedup vs baseline: 3.4149x; 1.3095x over previous
//
#include <hip/hip_runtime.h>
#include <hip/hip_bf16.h>
#include <math.h>

#define HDIM 100
#define NFACT 262144

using short8 = __attribute__((ext_vector_type(8))) short;
using f32x4  = __attribute__((ext_vector_type(4))) float;

// ---------------- ws float-offset layout ----------------
#define WS_B      0                       // 14336 floats = 7*8*64 uint4 B-fragments (bf16 bits)
#define WS_LOGITS 14336                   // NFACT
#define WS_BMAX   (WS_LOGITS + NFACT)     // 2048 per-block maxes
#define WS_GMAX   (WS_BMAX + 2048)        // 1
#define WS_SP     (WS_GMAX + 1)           // 1024 partial softmax denoms
#define WS_PC     (WS_SP + 1024)          // 1024*100 partial weighted sums [block][h]

__device__ __forceinline__ unsigned short f2bf(float x) {
    unsigned u = __builtin_bit_cast(unsigned, x);
    u += 0x7FFFu + ((u >> 16) & 1u);          // RNE round to bf16
    return (unsigned short)(u >> 16);
}

__device__ __forceinline__ float tanh_fast(float x) {
    float e = __expf(2.0f * x);
    return 1.0f - 2.0f / (1.0f + e);
}

// ---- Precompute W1 as MFMA B-fragments (bf16), frag order [jt][kc][lane][8] ----
// B[k][j]: j = jt*16 + (lane&15); k = kc*32 + (lane>>4)*8 + e.
// k in [0,128): half A (f - oc), real if (k&127) < 100; k in [128,256): half B (f - m).
__global__ __launch_bounds__(256) void k_prep_b(const float* __restrict__ W1,
                                                float* __restrict__ ws) {
    int t = blockIdx.x * 256 + threadIdx.x;   // 0..3583
    if (t >= 7 * 8 * 64) return;
    int lane = t & 63;
    int kc = (t >> 6) & 7;
    int jt = t >> 9;
    int g = lane >> 4, r = lane & 15;
    int j = jt * 16 + r;
    unsigned short v[8];
    #pragma unroll
    for (int e = 0; e < 8; e++) {
        int kglob = kc * 32 + g * 8 + e;
        int half = kglob >> 7;
        int koff = kglob & 127;
        float x = 0.f;
        if (j < HDIM && koff < HDIM) x = W1[j * 200 + half * HDIM + koff];
        v[e] = f2bf(x);
    }
    uint4 d;
    d.x = (unsigned)v[0] | ((unsigned)v[1] << 16);
    d.y = (unsigned)v[2] | ((unsigned)v[3] << 16);
    d.z = (unsigned)v[4] | ((unsigned)v[5] << 16);
    d.w = (unsigned)v[6] | ((unsigned)v[7] << 16);
    ((uint4*)(ws + WS_B))[t] = d;
}

__device__ __forceinline__ float4 ld4c(const float* p, bool ok) {
    float4 z = make_float4(0.f, 0.f, 0.f, 0.f);
    return ok ? *(const float4*)p : z;
}

__device__ __forceinline__ short8 absdiff_bf16(float4 a0, float4 a1,
                                               float4 b0, float4 b1) {
    union { __hip_bfloat16 h[8]; short8 v; } u;
    u.h[0] = __float2bfloat16(fabsf(a0.x - b0.x));
    u.h[1] = __float2bfloat16(fabsf(a0.y - b0.y));
    u.h[2] = __float2bfloat16(fabsf(a0.z - b0.z));
    u.h[3] = __float2bfloat16(fabsf(a0.w - b0.w));
    u.h[4] = __float2bfloat16(fabsf(a1.x - b1.x));
    u.h[5] = __float2bfloat16(fabsf(a1.y - b1.y));
    u.h[6] = __float2bfloat16(fabsf(a1.z - b1.z));
    u.h[7] = __float2bfloat16(fabsf(a1.w - b1.w));
    return u.v;
}

// 256 threads / 128 facts per block; A from global, B from ws (L2-resident).
__global__ __launch_bounds__(256, 3) void k_logits(
        const float* __restrict__ fe,
        const float* __restrict__ oc,
        const float* __restrict__ mvec,
        const float* __restrict__ b1,
        const float* __restrict__ W2,
        float* __restrict__ ws) {
    __shared__ float gv[128];
    __shared__ float red[4];
    int t = threadIdx.x;
    int w = t >> 6, lane = t & 63, g = lane >> 4, r = lane & 15;
    int n0 = blockIdx.x * 128;

    // Build A fragments straight from global. Halves share the same f values.
    short8 afrag[2][8];
    #pragma unroll
    for (int c = 0; c < 4; c++) {
        int base = c * 32 + g * 8;
        bool v0 = base < HDIM, v1 = base + 4 < HDIM;
        float4 oa = ld4c(oc + base, v0),   ob = ld4c(oc + base + 4, v1);
        float4 ma = ld4c(mvec + base, v0), mb = ld4c(mvec + base + 4, v1);
        #pragma unroll
        for (int tile = 0; tile < 2; tile++) {
            const float* fp = fe + (n0 + w * 32 + tile * 16 + r) * HDIM;
            float4 fa = ld4c(fp + base, v0), fb = ld4c(fp + base + 4, v1);
            afrag[tile][c]     = absdiff_bf16(fa, fb, oa, ob);   // |f - oc| half
            afrag[tile][4 + c] = absdiff_bf16(fa, fb, ma, mb);   // |f - m| half
        }
    }

    // GEMM over j-tiles; B double-buffered in registers from ws (L2).
    const uint4* Bg = (const uint4*)(ws + WS_B);
    uint4 bcur[8], bnxt[8];
    #pragma unroll
    for (int kc = 0; kc < 8; kc++) bcur[kc] = Bg[kc * 64 + lane];

    float gpart[2][4] = {{0, 0, 0, 0}, {0, 0, 0, 0}};
    #pragma unroll
    for (int jt = 0; jt < 7; jt++) {
        if (jt < 6) {
            #pragma unroll
            for (int kc = 0; kc < 8; kc++)
                bnxt[kc] = Bg[((jt + 1) * 8 + kc) * 64 + lane];
        }
        f32x4 acc0 = {0, 0, 0, 0}, acc1 = {0, 0, 0, 0};
        #pragma unroll
        for (int kc = 0; kc < 8; kc++) {
            short8 bv = __builtin_bit_cast(short8, bcur[kc]);
            acc0 = __builtin_amdgcn_mfma_f32_16x16x32_bf16(afrag[0][kc], bv, acc0, 0, 0, 0);
            acc1 = __builtin_amdgcn_mfma_f32_16x16x32_bf16(afrag[1][kc], bv, acc1, 0, 0, 0);
        }
        int j = jt * 16 + r;
        float w2j = (j < HDIM) ? W2[j] : 0.f;
        float b1j = (j < HDIM) ? b1[j] : 0.f;
        #pragma unroll
        for (int q = 0; q < 4; q++) {
            gpart[0][q] = fmaf(tanh_fast(acc0[q] + b1j), w2j, gpart[0][q]);
            gpart[1][q] = fmaf(tanh_fast(acc1[q] + b1j), w2j, gpart[1][q]);
        }
        #pragma unroll
        for (int kc = 0; kc < 8; kc++) bcur[kc] = bnxt[kc];
    }

    // reduce over j (lane&15); C row = fact = g*4+q within tile
    #pragma unroll
    for (int tile = 0; tile < 2; tile++) {
        #pragma unroll
        for (int q = 0; q < 4; q++) {
            float v = gpart[tile][q];
            v += __shfl_xor(v, 1); v += __shfl_xor(v, 2);
            v += __shfl_xor(v, 4); v += __shfl_xor(v, 8);
            if (r == 0) gv[w * 32 + tile * 16 + g * 4 + q] = v;
        }
    }
    __syncthreads();

    float logit = -1e30f;
    if (t < 128) {
        logit = gv[t];                       // b2 dropped: softmax-invariant
        ws[WS_LOGITS + n0 + t] = logit;
    }
    float mv = logit;
    #pragma unroll
    for (int off = 32; off; off >>= 1) mv = fmaxf(mv, __shfl_down(mv, off));
    if ((t & 63) == 0) red[t >> 6] = mv;
    __syncthreads();
    if (t == 0)
        ws[WS_BMAX + blockIdx.x] = fmaxf(fmaxf(red[0], red[1]),
                                         fmaxf(red[2], red[3]));
}

__global__ __launch_bounds__(256) void k_gmax(float* __restrict__ ws) {
    __shared__ float red[4];
    int t = threadIdx.x;
    float mv = -1e30f;
    for (int i = t; i < 2048; i += 256) mv = fmaxf(mv, ws[WS_BMAX + i]);
    #pragma unroll
    for (int off = 32; off; off >>= 1) mv = fmaxf(mv, __shfl_down(mv, off));
    if ((t & 63) == 0) red[t >> 6] = mv;
    __syncthreads();
    if (t == 0) ws[WS_GMAX] = fmaxf(fmaxf(red[0], red[1]), fmaxf(red[2], red[3]));
}

// 256 facts/block; per-block partial S and partial c[100] (no atomics)
__global__ __launch_bounds__(256) void k_wsum(const float* __restrict__ fe,
                                              float* __restrict__ ws) {
    __shared__ float wls[256];
    __shared__ float sred[4];
    __shared__ float4 cp[10][25];
    int t = threadIdx.x;
    long n0 = (long)blockIdx.x * 256;
    float gmax = ws[WS_GMAX];
    float lw = __expf(ws[WS_LOGITS + n0 + t] - gmax);
    wls[t] = lw;
    float s = lw;
    #pragma unroll
    for (int off = 32; off; off >>= 1) s += __shfl_down(s, off);
    if ((t & 63) == 0) sred[t >> 6] = s;
    __syncthreads();
    if (t == 0) ws[WS_SP + blockIdx.x] = (sred[0] + sred[1]) + (sred[2] + sred[3]);

    if (t < 250) {
        int sl = t / 25, p = t % 25;
        const float4* f4 = (const float4*)(fe + n0 * HDIM);
        float4 c = make_float4(0.f, 0.f, 0.f, 0.f);
        #pragma unroll 4
        for (int n = sl; n < 256; n += 10) {
            float wn = wls[n];
            float4 v = f4[n * 25 + p];
            c.x = fmaf(wn, v.x, c.x);
            c.y = fmaf(wn, v.y, c.y);
            c.z = fmaf(wn, v.z, c.z);
            c.w = fmaf(wn, v.w, c.w);
        }
        cp[sl][p] = c;
    }
    __syncthreads();
    if (t < 25) {
        float4 c = make_float4(0.f, 0.f, 0.f, 0.f);
        #pragma unroll
        for (int sl = 0; sl < 10; sl++) {
            float4 v = cp[sl][t];
            c.x += v.x; c.y += v.y; c.z += v.z; c.w += v.w;
        }
        *(float4*)(ws + WS_PC + blockIdx.x * HDIM + t * 4) = c;
    }
}

// Sum partials, normalize, gated update
__global__ __launch_bounds__(1024) void k_final(
        const float* __restrict__ mvec,
        const float* __restrict__ oc,
        const float* __restrict__ W3,
        const float* __restrict__ b3,
        const float* __restrict__ ws,
        float* __restrict__ out) {
    __shared__ float sr[256];
    __shared__ float csl[1000];
    __shared__ float vv[300];
    __shared__ float Sval;
    int t = threadIdx.x;
    if (t < 256) {
        float a = 0.f;
        #pragma unroll
        for (int k = 0; k < 4; k++) a += ws[WS_SP + t + k * 256];
        sr[t] = a;
    }
    __syncthreads();
    if (t < 128) sr[t] += sr[t + 128];
    __syncthreads();
    if (t < 64) sr[t] += sr[t + 64];
    __syncthreads();
    if (t == 0) {
        float a = 0.f;
        #pragma unroll
        for (int k = 0; k < 64; k++) a += sr[k];
        Sval = a;
    }
    if (t < 1000) {
        int sl = t / 100, h = t % 100;
        float a = 0.f;
        #pragma unroll 4
        for (int b = sl; b < 1024; b += 10) a += ws[WS_PC + b * HDIM + h];
        csl[t] = a;
    }
    __syncthreads();
    if (t < 100) {
        float c = 0.f;
        #pragma unroll
        for (int sl = 0; sl < 10; sl++) c += csl[sl * 100 + t];
        vv[t] = mvec[t];
        vv[100 + t] = c / Sval;
        vv[200 + t] = oc[t];
    }
    __syncthreads();
    if (t < 100) {
        float a = b3[t];
        const float* wr = W3 + t * 300;
        #pragma unroll 4
        for (int k = 0; k < 300; k++) a = fmaf(wr[k], vv[k], a);
        out[t] = fmaxf(a, 0.f);
    }
}

extern "C" void kernel_launch(void* const* d_in, const int* in_sizes, int n_in,
                              void* d_out, int out_size, void* d_ws, size_t ws_size,
                              hipStream_t stream) {
    const float* mvec = (const float*)d_in[0];
    const float* oh   = (const float*)d_in[1];
    const float* fe   = (const float*)d_in[2];
    const float* W1   = (const float*)d_in[3];
    const float* b1   = (const float*)d_in[4];
    const float* W2   = (const float*)d_in[5];
    const float* W3   = (const float*)d_in[7];
    const float* b3   = (const float*)d_in[8];
    float* ws  = (float*)d_ws;
    float* out = (float*)d_out;

    k_prep_b<<<14, 256, 0, stream>>>(W1, ws);
    k_logits<<<NFACT / 128, 256, 0, stream>>>(fe, oh, mvec, b1, W2, ws);
    k_gmax<<<1, 256, 0, stream>>>(ws);
    k_wsum<<<NFACT / 256, 256, 0, stream>>>(fe, ws);
    k_final<<<1, 1024, 0, stream>>>(mvec, oh, W3, b3, ws, out);
}

// Round 4
// 93.698 us; speedup vs baseline: 3.8329x; 1.1224x over previous
//
#include <hip/hip_runtime.h>
#include <hip/hip_bf16.h>
#include <math.h>

#define HDIM 100
#define NFACT 262144
#define NBLK  1024            // NFACT / 256

using short8 = __attribute__((ext_vector_type(8))) short;
using f32x4  = __attribute__((ext_vector_type(4))) float;

// ---------------- ws float-offset layout ----------------
#define WS_B     0                    // 14336 floats = 7*8*64 uint4 B-fragments (bf16 bits)
#define WS_BMAX  14336                // NBLK per-block maxes
#define WS_SP    (WS_BMAX + NBLK)     // NBLK partial softmax denoms
#define WS_PC    (WS_SP + NBLK)       // NBLK*100 partial weighted sums [block][h]
// end = 16384 + 102400 = 118784 floats (~464 KB)

__device__ __forceinline__ unsigned short f2bf(float x) {
    unsigned u = __builtin_bit_cast(unsigned, x);
    u += 0x7FFFu + ((u >> 16) & 1u);          // RNE round to bf16
    return (unsigned short)(u >> 16);
}

__device__ __forceinline__ float tanh_fast(float x) {
    float e = __expf(2.0f * x);
    return 1.0f - 2.0f / (1.0f + e);
}

// ---- Precompute W1 as MFMA B-fragments (bf16), frag order [jt][kc][lane][8] ----
// B[k][j]: j = jt*16 + (lane&15); k = kc*32 + (lane>>4)*8 + e.
// k in [0,128): half A (f - oc), real if (k&127) < 100; k in [128,256): half B (f - m).
__global__ __launch_bounds__(256) void k_prep_b(const float* __restrict__ W1,
                                                float* __restrict__ ws) {
    int t = blockIdx.x * 256 + threadIdx.x;   // 0..3583
    if (t >= 7 * 8 * 64) return;
    int lane = t & 63;
    int kc = (t >> 6) & 7;
    int jt = t >> 9;
    int g = lane >> 4, r = lane & 15;
    int j = jt * 16 + r;
    unsigned short v[8];
    #pragma unroll
    for (int e = 0; e < 8; e++) {
        int kglob = kc * 32 + g * 8 + e;
        int half = kglob >> 7;
        int koff = kglob & 127;
        float x = 0.f;
        if (j < HDIM && koff < HDIM) x = W1[j * 200 + half * HDIM + koff];
        v[e] = f2bf(x);
    }
    uint4 d;
    d.x = (unsigned)v[0] | ((unsigned)v[1] << 16);
    d.y = (unsigned)v[2] | ((unsigned)v[3] << 16);
    d.z = (unsigned)v[4] | ((unsigned)v[5] << 16);
    d.w = (unsigned)v[6] | ((unsigned)v[7] << 16);
    ((uint4*)(ws + WS_B))[t] = d;
}

__device__ __forceinline__ float4 ld4c(const float* p, bool ok) {
    float4 z = make_float4(0.f, 0.f, 0.f, 0.f);
    return ok ? *(const float4*)p : z;
}

__device__ __forceinline__ short8 absdiff_bf16(float4 a0, float4 a1,
                                               float4 b0, float4 b1) {
    union { __hip_bfloat16 h[8]; short8 v; } u;
    u.h[0] = __float2bfloat16(fabsf(a0.x - b0.x));
    u.h[1] = __float2bfloat16(fabsf(a0.y - b0.y));
    u.h[2] = __float2bfloat16(fabsf(a0.z - b0.z));
    u.h[3] = __float2bfloat16(fabsf(a0.w - b0.w));
    u.h[4] = __float2bfloat16(fabsf(a1.x - b1.x));
    u.h[5] = __float2bfloat16(fabsf(a1.y - b1.y));
    u.h[6] = __float2bfloat16(fabsf(a1.z - b1.z));
    u.h[7] = __float2bfloat16(fabsf(a1.w - b1.w));
    return u.v;
}

// Fused: logits (MFMA) + per-block softmax partials + per-block weighted pooling.
// 512 threads (8 waves), 256 facts/block, B staged once in LDS.
__global__ __launch_bounds__(512, 4) void k_logits(
        const float* __restrict__ fe,
        const float* __restrict__ oc,
        const float* __restrict__ mvec,
        const float* __restrict__ b1,
        const float* __restrict__ W2,
        float* __restrict__ ws) {
    __shared__ uint4 Bs[3584];           // 57344 B
    __shared__ float gv[256];
    __shared__ float wls[256];
    __shared__ float red[8];
    __shared__ float sred[8];
    __shared__ float4 cp[20][25];        // 8 KB pooling scratch

    int t = threadIdx.x;
    int w = t >> 6, lane = t & 63, g = lane >> 4, r = lane & 15;
    int n0 = blockIdx.x * 256;

    // stage B fragments (57344 B) from ws (L2-resident)
    {
        const uint4* src = (const uint4*)(ws + WS_B);
        #pragma unroll
        for (int i = 0; i < 7; i++) Bs[t + i * 512] = src[t + i * 512];
    }

    // Build A fragments straight from global. Halves share the same f values.
    short8 afrag[2][8];
    #pragma unroll
    for (int c = 0; c < 4; c++) {
        int base = c * 32 + g * 8;
        bool v0 = base < HDIM, v1 = base + 4 < HDIM;
        float4 oa = ld4c(oc + base, v0),   ob = ld4c(oc + base + 4, v1);
        float4 ma = ld4c(mvec + base, v0), mb = ld4c(mvec + base + 4, v1);
        #pragma unroll
        for (int tile = 0; tile < 2; tile++) {
            const float* fp = fe + (n0 + w * 32 + tile * 16 + r) * HDIM;
            float4 fa = ld4c(fp + base, v0), fb = ld4c(fp + base + 4, v1);
            afrag[tile][c]     = absdiff_bf16(fa, fb, oa, ob);   // |f - oc| half
            afrag[tile][4 + c] = absdiff_bf16(fa, fb, ma, mb);   // |f - m| half
        }
    }
    __syncthreads();

    // GEMM over j-tiles; B from LDS (shared by all 8 waves).
    float gpart[2][4] = {{0, 0, 0, 0}, {0, 0, 0, 0}};
    #pragma unroll
    for (int jt = 0; jt < 7; jt++) {
        f32x4 acc0 = {0, 0, 0, 0}, acc1 = {0, 0, 0, 0};
        #pragma unroll
        for (int kc = 0; kc < 8; kc++) {
            short8 bv = __builtin_bit_cast(short8, Bs[(jt * 8 + kc) * 64 + lane]);
            acc0 = __builtin_amdgcn_mfma_f32_16x16x32_bf16(afrag[0][kc], bv, acc0, 0, 0, 0);
            acc1 = __builtin_amdgcn_mfma_f32_16x16x32_bf16(afrag[1][kc], bv, acc1, 0, 0, 0);
        }
        int j = jt * 16 + r;
        float w2j = (j < HDIM) ? W2[j] : 0.f;
        float b1j = (j < HDIM) ? b1[j] : 0.f;
        #pragma unroll
        for (int q = 0; q < 4; q++) {
            gpart[0][q] = fmaf(tanh_fast(acc0[q] + b1j), w2j, gpart[0][q]);
            gpart[1][q] = fmaf(tanh_fast(acc1[q] + b1j), w2j, gpart[1][q]);
        }
    }

    // reduce over j (lane&15); C row = fact = g*4+q within tile (b2 dropped: softmax-invariant)
    #pragma unroll
    for (int tile = 0; tile < 2; tile++) {
        #pragma unroll
        for (int q = 0; q < 4; q++) {
            float v = gpart[tile][q];
            v += __shfl_xor(v, 1); v += __shfl_xor(v, 2);
            v += __shfl_xor(v, 4); v += __shfl_xor(v, 8);
            if (r == 0) gv[w * 32 + tile * 16 + g * 4 + q] = v;
        }
    }
    __syncthreads();

    // block max over 256 logits
    float mv = (t < 256) ? gv[t] : -1e30f;
    float m2 = mv;
    #pragma unroll
    for (int off = 32; off; off >>= 1) m2 = fmaxf(m2, __shfl_down(m2, off));
    if (lane == 0) red[w] = m2;
    __syncthreads();
    float bmax = red[0];
    #pragma unroll
    for (int i = 1; i < 8; i++) bmax = fmaxf(bmax, red[i]);

    // weights + partial denom
    float lw = (t < 256) ? __expf(mv - bmax) : 0.f;
    if (t < 256) wls[t] = lw;
    float s = lw;
    #pragma unroll
    for (int off = 32; off; off >>= 1) s += __shfl_down(s, off);
    if (lane == 0) sred[w] = s;
    __syncthreads();

    if (t == 0) {
        float S_p = 0.f;
        #pragma unroll
        for (int i = 0; i < 8; i++) S_p += sred[i];
        ws[WS_SP + blockIdx.x] = S_p;
        ws[WS_BMAX + blockIdx.x] = bmax;
    }

    // partial weighted pooling: c_p[k] = sum_n wls[n] * fe[n0+n][k]  (fe rows L2-hot)
    if (t < 500) {
        int sl = t / 25, p = t % 25;
        const float4* f4 = (const float4*)(fe + (long)n0 * HDIM);
        float4 c = make_float4(0.f, 0.f, 0.f, 0.f);
        for (int n = sl; n < 256; n += 20) {
            float wn = wls[n];
            float4 v = f4[n * 25 + p];
            c.x = fmaf(wn, v.x, c.x);
            c.y = fmaf(wn, v.y, c.y);
            c.z = fmaf(wn, v.z, c.z);
            c.w = fmaf(wn, v.w, c.w);
        }
        cp[sl][p] = c;
    }
    __syncthreads();
    if (t < 25) {
        float4 c = make_float4(0.f, 0.f, 0.f, 0.f);
        #pragma unroll
        for (int sl = 0; sl < 20; sl++) {
            float4 v = cp[sl][t];
            c.x += v.x; c.y += v.y; c.z += v.z; c.w += v.w;
        }
        *(float4*)(ws + WS_PC + (long)blockIdx.x * HDIM + t * 4) = c;
    }
}

// Combine per-block partials (flash-style), normalize, gated update. One block.
__global__ __launch_bounds__(1024) void k_final(
        const float* __restrict__ mvec,
        const float* __restrict__ oc,
        const float* __restrict__ W3,
        const float* __restrict__ b3,
        const float* __restrict__ ws,
        float* __restrict__ out) {
    __shared__ float red16[16];
    __shared__ float scl[NBLK];
    __shared__ float sred[4];
    __shared__ float csl[1000];
    __shared__ float vv[300];
    __shared__ float Sval;
    int t = threadIdx.x;
    int w = t >> 6, lane = t & 63;

    // global max over per-block maxes
    float bm = ws[WS_BMAX + t];
    float m2 = bm;
    #pragma unroll
    for (int off = 32; off; off >>= 1) m2 = fmaxf(m2, __shfl_down(m2, off));
    if (lane == 0) red16[w] = m2;
    __syncthreads();
    float gmax = red16[0];
    #pragma unroll
    for (int i = 1; i < 16; i++) gmax = fmaxf(gmax, red16[i]);

    // per-block scales
    scl[t] = __expf(bm - gmax);
    __syncthreads();

    // S = sum scl_b * S_b  (256 threads)
    if (t < 256) {
        float s = 0.f;
        #pragma unroll
        for (int k = 0; k < 4; k++) s += scl[t + k * 256] * ws[WS_SP + t + k * 256];
        #pragma unroll
        for (int off = 32; off; off >>= 1) s += __shfl_down(s, off);
        if (lane == 0) sred[w] = s;
    }
    // c[h] partials over block-slices (1000 threads)
    if (t < 1000) {
        int sl = t / 100, h = t % 100;
        float a = 0.f;
        #pragma unroll 4
        for (int b = sl; b < NBLK; b += 10) a += scl[b] * ws[WS_PC + b * HDIM + h];
        csl[t] = a;
    }
    __syncthreads();
    if (t == 0) Sval = (sred[0] + sred[1]) + (sred[2] + sred[3]);
    __syncthreads();
    if (t < 100) {
        float c = 0.f;
        #pragma unroll
        for (int sl = 0; sl < 10; sl++) c += csl[sl * 100 + t];
        vv[t] = mvec[t];
        vv[100 + t] = c / Sval;
        vv[200 + t] = oc[t];
    }
    __syncthreads();
    if (t < 100) {
        float a = b3[t];
        const float* wr = W3 + t * 300;
        #pragma unroll 4
        for (int k = 0; k < 300; k++) a = fmaf(wr[k], vv[k], a);
        out[t] = fmaxf(a, 0.f);
    }
}

extern "C" void kernel_launch(void* const* d_in, const int* in_sizes, int n_in,
                              void* d_out, int out_size, void* d_ws, size_t ws_size,
                              hipStream_t stream) {
    const float* mvec = (const float*)d_in[0];
    const float* oh   = (const float*)d_in[1];
    const float* fe   = (const float*)d_in[2];
    const float* W1   = (const float*)d_in[3];
    const float* b1   = (const float*)d_in[4];
    const float* W2   = (const float*)d_in[5];
    const float* W3   = (const float*)d_in[7];
    const float* b3   = (const float*)d_in[8];
    float* ws  = (float*)d_ws;
    float* out = (float*)d_out;

    k_prep_b<<<14, 256, 0, stream>>>(W1, ws);
    k_logits<<<NBLK, 512, 0, stream>>>(fe, oh, mvec, b1, W2, ws);
    k_final<<<1, 1024, 0, stream>>>(mvec, oh, W3, b3, ws, out);
}